// Round 7
// baseline (285.584 us; speedup 1.0000x reference)
//
#include <hip/hip_runtime.h>
#include <hip/hip_bf16.h>
#include <stdint.h>

typedef __attribute__((ext_vector_type(8))) short s16x8;
typedef __attribute__((ext_vector_type(4))) float f32x4;

__device__ __forceinline__ unsigned short f32_bf16(float f) {
  union { float f; uint32_t u; } v; v.f = f;
  return (unsigned short)((v.u + 0x7FFFu + ((v.u >> 16) & 1u)) >> 16);
}

__device__ __forceinline__ uint32_t pack_bf16(float lo, float hi) {
  __hip_bfloat162 h = __float22bfloat162_rn(float2{lo, hi});
  union { __hip_bfloat162 h; uint32_t u; } u; u.h = h; return u.u;
}

// Exchange 4-row chunks across the four 16-lane groups to build an MFMA
// A-fragment (k = 8*l4 + j) from C-fragment-resident data (lane = row).
__device__ __forceinline__ s16x8 xchg(uint32_t lo0, uint32_t lo1,
                                      uint32_t hi0, uint32_t hi1,
                                      int srcA, int srcB, uint32_t hisel) {
  int a0 = __shfl((int)lo0, srcA), b0 = __shfl((int)hi0, srcA);
  int a1 = __shfl((int)lo1, srcA), b1 = __shfl((int)hi1, srcA);
  int a2 = __shfl((int)lo0, srcB), b2 = __shfl((int)hi0, srcB);
  int a3 = __shfl((int)lo1, srcB), b3 = __shfl((int)hi1, srcB);
  union { uint32_t u[4]; s16x8 v; } r;
  r.u[0] = hisel ? (uint32_t)b0 : (uint32_t)a0;
  r.u[1] = hisel ? (uint32_t)b1 : (uint32_t)a1;
  r.u[2] = hisel ? (uint32_t)b2 : (uint32_t)a2;
  r.u[3] = hisel ? (uint32_t)b3 : (uint32_t)a3;
  return r.v;
}

// ---------------- kernel 1: weights f32 -> bf16 ----------------
__global__ void convert_w(const float* __restrict__ wqkv,
                          const float* __restrict__ wout,
                          unsigned short* __restrict__ o) {
  int i = blockIdx.x * 256 + threadIdx.x;           // 262144 total
  if (i < 768 * 256) o[i] = f32_bf16(wqkv[i]);
  else               o[i] = f32_bf16(wout[i - 768 * 256]);
}

// -------- kernel 2: QKV GEMM (M=131072, N=768, K=256), swapped-C --------
// 128x128 tiles, 4 waves (2x2), BK=64, reg-staged swizzled LDS.
// mfma(A=w-frag, B=x-frag) -> C[wcol][tok]; stores pack 4 consecutive
// wcols per uint2. q,k go to per-group regions of d_out (scratch);
// v to per-group regions of d_ws.
__global__ __launch_bounds__(256) void qkv_gemm(
    const float* __restrict__ x,           // [131072][256] f32
    const unsigned short* __restrict__ wq, // [768][256] bf16
    unsigned short* qk_out,                // d_out: per group 64KB {q 32K | k 32K}
    unsigned short* v_out) {               // ws: per group 32KB v[t64][256]
  __shared__ unsigned short As[128 * 64];
  __shared__ unsigned short Bs[128 * 64];
  const int bm = blockIdx.x, bn = blockIdx.y;
  const int tid = threadIdx.x;
  const int w = tid >> 6, lane = tid & 63;
  const int l15 = lane & 15, l4 = lane >> 4;
  const int wr = w >> 1, wc = w & 1;
  const uint32_t swz = (uint32_t)(l15 & 7) << 4;

  f32x4 acc[4][4];
#pragma unroll
  for (int mi = 0; mi < 4; ++mi)
#pragma unroll
    for (int ni = 0; ni < 4; ++ni) acc[mi][ni] = (f32x4){0.f, 0.f, 0.f, 0.f};

  const int srow = tid >> 1;
  const int sc0  = (tid & 1) * 32;
  const float* ga = x + (size_t)(bm * 128 + srow) * 256 + sc0;
  const unsigned short* gb = wq + (size_t)(bn * 128 + srow) * 256 + sc0;
  const uint32_t sbyte0 = (uint32_t)(srow * 128 + sc0 * 2);
  const uint32_t ssw = (uint32_t)(srow & 7) << 4;

  for (int kk = 0; kk < 4; ++kk) {
#pragma unroll
    for (int c = 0; c < 32; c += 8) {
      float4 f0 = *(const float4*)(ga + kk * 64 + c);
      float4 f1 = *(const float4*)(ga + kk * 64 + c + 4);
      uint4 vb = *(const uint4*)(gb + kk * 64 + c);
      uint32_t byte = (sbyte0 + c * 2) ^ ssw;
      *(uint4*)((char*)As + byte) =
          make_uint4(pack_bf16(f0.x, f0.y), pack_bf16(f0.z, f0.w),
                     pack_bf16(f1.x, f1.y), pack_bf16(f1.z, f1.w));
      *(uint4*)((char*)Bs + byte) = vb;
    }
    __syncthreads();
#pragma unroll
    for (int k2 = 0; k2 < 2; ++k2) {
      s16x8 af[4], bf[4];
#pragma unroll
      for (int mi = 0; mi < 4; ++mi) {
        int row = wr * 64 + 16 * mi + l15;
        uint32_t byte = (uint32_t)(row * 128 + k2 * 64 + l4 * 16) ^ ((row & 7) << 4);
        af[mi] = *(const s16x8*)((const char*)Bs + byte);   // w rows (A-op)
      }
#pragma unroll
      for (int ni = 0; ni < 4; ++ni) {
        int row = wc * 64 + 16 * ni + l15;
        uint32_t byte = (uint32_t)(row * 128 + k2 * 64 + l4 * 16) ^ ((row & 7) << 4);
        bf[ni] = *(const s16x8*)((const char*)As + byte);   // x rows (B-op)
      }
#pragma unroll
      for (int mi = 0; mi < 4; ++mi)
#pragma unroll
        for (int ni = 0; ni < 4; ++ni)
          acc[mi][ni] = __builtin_amdgcn_mfma_f32_16x16x32_bf16(af[mi], bf[ni], acc[mi][ni], 0, 0, 0);
    }
    __syncthreads();
  }

  // C[wcol][tok]: g = bm*2 + wc, t64 = 16ni + l15, wcol = bn*128+wr*64+16mi+4*l4+r
  const int g = bm * 2 + wc;
  if (bn < 4) {
    char* base = (char*)qk_out + ((size_t)g << 16) + ((bn & 2) ? 32768 : 0);
    const int colb = (bn & 1) * 128 + wr * 64 + 4 * l4;
#pragma unroll
    for (int mi = 0; mi < 4; ++mi)
#pragma unroll
      for (int ni = 0; ni < 4; ++ni) {
        uint2 st = make_uint2(pack_bf16(acc[mi][ni][0], acc[mi][ni][1]),
                              pack_bf16(acc[mi][ni][2], acc[mi][ni][3]));
        *(uint2*)(base + (16 * ni + l15) * 512 + (colb + 16 * mi) * 2) = st;
      }
  } else {
    char* base = (char*)v_out + ((size_t)g << 15);
    const int colb = (bn - 4) * 128 + wr * 64 + 4 * l4;
#pragma unroll
    for (int mi = 0; mi < 4; ++mi)
#pragma unroll
      for (int ni = 0; ni < 4; ++ni) {
        uint2 st = make_uint2(pack_bf16(acc[mi][ni][0], acc[mi][ni][1]),
                              pack_bf16(acc[mi][ni][2], acc[mi][ni][3]));
        *(uint2*)(base + (16 * ni + l15) * 512 + (colb + 16 * mi) * 2) = st;
      }
  }
}

// -------- kernel 3: attention + out-projection, block per group ---------
// 8 waves = 8 heads. q/k read as native fragments from d_out region g,
// v via scalar reads from ws. In-register softmax; PV via xchg. o staged
// in 32KB LDS (1 barrier), then swapped-operand projection + bias,
// coalesced float4 stores overwrite region g of out.
__global__ __launch_bounds__(512) void attn_proj(
    const unsigned short* qk,              // d_out scratch (aliases out!)
    const unsigned short* __restrict__ v_buf,
    const unsigned short* __restrict__ wo, // [256][256] bf16
    const float* __restrict__ bias,
    float* out) {
  __shared__ unsigned short ot[64 * 256];  // 32 KB attn-out tile, swz rows

  const int g    = blockIdx.x;
  const int tid  = threadIdx.x;
  const int h    = tid >> 6;
  const int lane = tid & 63;
  const int l15  = lane & 15;
  const int l4   = lane >> 4;
  const int      srcA  = l15 + ((lane & 16) << 1);
  const int      srcB  = srcA + 16;
  const uint32_t hisel = (uint32_t)(lane & 32);

  const char* qbase = (const char*)qk + ((size_t)g << 16);
  const int hcolb = (h * 32 + l4 * 8) * 2;

  // ---- load q,k fragments (b128 global) ----
  s16x8 kA[4], qB[4];
#pragma unroll
  for (int mb = 0; mb < 4; ++mb)
    kA[mb] = *(const s16x8*)(qbase + 32768 + (16 * mb + l15) * 512 + hcolb);
#pragma unroll
  for (int nb = 0; nb < 4; ++nb)
    qB[nb] = *(const s16x8*)(qbase + (16 * nb + l15) * 512 + hcolb);

  // ---- load v fragments (scalar u16, B-frag: lane=d col, k=ktok) ----
  s16x8 vB[2][2];
  const char* vb0 = (const char*)v_buf + ((size_t)g << 15);
#pragma unroll
  for (int kk2 = 0; kk2 < 2; ++kk2)
#pragma unroll
    for (int t = 0; t < 2; ++t) {
      union { unsigned short u[8]; s16x8 v; } uv;
      const char* vp = vb0 + (kk2 * 32 + 8 * l4) * 512 + (h * 32 + 16 * t + l15) * 2;
#pragma unroll
      for (int j = 0; j < 8; ++j)
        uv.u[j] = *(const unsigned short*)(vp + j * 512);
      vB[kk2][t] = uv.v;
    }

  // ---- per q-block: energy^T -> softmax -> PV -> LDS store ----
#pragma unroll
  for (int nb = 0; nb < 4; ++nb) {
    f32x4 en[4];
#pragma unroll
    for (int mb = 0; mb < 4; ++mb) {
      en[mb] = (f32x4){0.f, 0.f, 0.f, 0.f};
      en[mb] = __builtin_amdgcn_mfma_f32_16x16x32_bf16(kA[mb], qB[nb], en[mb], 0, 0, 0);
    }
    float mx = en[0][0];
#pragma unroll
    for (int mb = 0; mb < 4; ++mb)
#pragma unroll
      for (int r = 0; r < 4; ++r) mx = fmaxf(mx, en[mb][r]);
    mx = fmaxf(mx, __shfl_xor(mx, 16));
    mx = fmaxf(mx, __shfl_xor(mx, 32));
    float p[4][4];
    float sum = 0.f;
#pragma unroll
    for (int mb = 0; mb < 4; ++mb)
#pragma unroll
      for (int r = 0; r < 4; ++r) {
        float t = __expf((en[mb][r] - mx) * 0.0625f);  // scale 1/sqrt(256)
        p[mb][r] = t;
        sum += t;
      }
    sum += __shfl_xor(sum, 16);
    sum += __shfl_xor(sum, 32);
    float rs = 1.0f / sum;
    uint32_t pk[4][2];
#pragma unroll
    for (int mb = 0; mb < 4; ++mb) {
      pk[mb][0] = pack_bf16(p[mb][0] * rs, p[mb][1] * rs);
      pk[mb][1] = pack_bf16(p[mb][2] * rs, p[mb][3] * rs);
    }
    f32x4 o0 = (f32x4){0.f, 0.f, 0.f, 0.f};
    f32x4 o1 = (f32x4){0.f, 0.f, 0.f, 0.f};
#pragma unroll
    for (int kk2 = 0; kk2 < 2; ++kk2) {
      s16x8 pA = xchg(pk[2 * kk2][0], pk[2 * kk2][1],
                      pk[2 * kk2 + 1][0], pk[2 * kk2 + 1][1], srcA, srcB, hisel);
      o0 = __builtin_amdgcn_mfma_f32_16x16x32_bf16(pA, vB[kk2][0], o0, 0, 0, 0);
      o1 = __builtin_amdgcn_mfma_f32_16x16x32_bf16(pA, vB[kk2][1], o1, 0, 0, 0);
    }
#pragma unroll
    for (int r = 0; r < 4; ++r) {
      int row = 16 * nb + 4 * l4 + r;
      uint32_t rsw = (uint32_t)(row & 7) << 4;
      uint32_t c0 = ((uint32_t)(row * 512 + (h * 32 + l15) * 2)) ^ rsw;
      uint32_t c1 = ((uint32_t)(row * 512 + (h * 32 + 16 + l15) * 2)) ^ rsw;
      *(unsigned short*)((char*)ot + c0) = f32_bf16(o0[r]);
      *(unsigned short*)((char*)ot + c1) = f32_bf16(o1[r]);
    }
  }
  __syncthreads();

  // ---- projection: wave h -> out cols [h*32, h*32+32), swapped C ----
  f32x4 acc2[2][4];
#pragma unroll
  for (int mi = 0; mi < 2; ++mi)
#pragma unroll
    for (int ni = 0; ni < 4; ++ni) acc2[mi][ni] = (f32x4){0.f, 0.f, 0.f, 0.f};

#pragma unroll
  for (int kk = 0; kk < 8; ++kk) {
    s16x8 af[2], bfrag[4];
#pragma unroll
    for (int mi = 0; mi < 2; ++mi)
      af[mi] = *(const s16x8*)(wo + (size_t)(h * 32 + 16 * mi + l15) * 256 + kk * 32 + l4 * 8);
#pragma unroll
    for (int ni = 0; ni < 4; ++ni) {
      uint32_t byte = ((uint32_t)((16 * ni + l15) * 512 + (kk * 32 + l4 * 8) * 2)) ^ ((uint32_t)(l15 & 7) << 4);
      bfrag[ni] = *(const s16x8*)((const char*)ot + byte);
    }
#pragma unroll
    for (int mi = 0; mi < 2; ++mi)
#pragma unroll
      for (int ni = 0; ni < 4; ++ni)
        acc2[mi][ni] = __builtin_amdgcn_mfma_f32_16x16x32_bf16(af[mi], bfrag[ni], acc2[mi][ni], 0, 0, 0);
  }

#pragma unroll
  for (int mi = 0; mi < 2; ++mi) {
    const int oc = h * 32 + 16 * mi + 4 * l4;
    float4 bb = *(const float4*)(bias + oc);
#pragma unroll
    for (int ni = 0; ni < 4; ++ni) {
      float4 st;
      st.x = acc2[mi][ni][0] + bb.x;
      st.y = acc2[mi][ni][1] + bb.y;
      st.z = acc2[mi][ni][2] + bb.z;
      st.w = acc2[mi][ni][3] + bb.w;
      *(float4*)(out + (size_t)(g * 64 + 16 * ni + l15) * 256 + oc) = st;
    }
  }
}

extern "C" void kernel_launch(void* const* d_in, const int* in_sizes, int n_in,
                              void* d_out, int out_size, void* d_ws, size_t ws_size,
                              hipStream_t stream) {
  const float* x    = (const float*)d_in[0];
  const float* wqkv = (const float*)d_in[1];
  const float* wout = (const float*)d_in[2];
  const float* bout = (const float*)d_in[3];
  float* out = (float*)d_out;

  unsigned short* wq_bf = (unsigned short*)d_ws;          // 768*256 bf16
  unsigned short* wo_bf = wq_bf + 768 * 256;              // 256*256 bf16
  unsigned short* v_buf = wo_bf + 256 * 256;              // 2048 groups * 32KB

  convert_w<<<1024, 256, 0, stream>>>(wqkv, wout, wq_bf);
  qkv_gemm<<<dim3(1024, 6), 256, 0, stream>>>(x, wq_bf, (unsigned short*)d_out, v_buf);
  attn_proj<<<2048, 512, 0, stream>>>((const unsigned short*)d_out, v_buf, wo_bf, bout, out);
}

// Round 8
// 238.703 us; speedup vs baseline: 1.1964x; 1.1964x over previous
//
#include <hip/hip_runtime.h>
#include <hip/hip_bf16.h>
#include <stdint.h>

typedef __attribute__((ext_vector_type(8))) short s16x8;
typedef __attribute__((ext_vector_type(4))) float f32x4;

__device__ __forceinline__ unsigned short f32_bf16(float f) {
  union { float f; uint32_t u; } v; v.f = f;
  return (unsigned short)((v.u + 0x7FFFu + ((v.u >> 16) & 1u)) >> 16);
}

__device__ __forceinline__ uint32_t pack_bf16(float lo, float hi) {
  __hip_bfloat162 h = __float22bfloat162_rn(float2{lo, hi});
  union { __hip_bfloat162 h; uint32_t u; } u; u.h = h; return u.u;
}

// Exchange 4-row chunks across the four 16-lane groups to build an MFMA
// A-fragment (k = 8*l4 + j) from C-fragment-resident data (lane = row).
__device__ __forceinline__ s16x8 xchg(uint32_t lo0, uint32_t lo1,
                                      uint32_t hi0, uint32_t hi1,
                                      int srcA, int srcB, uint32_t hisel) {
  int a0 = __shfl((int)lo0, srcA), b0 = __shfl((int)hi0, srcA);
  int a1 = __shfl((int)lo1, srcA), b1 = __shfl((int)hi1, srcA);
  int a2 = __shfl((int)lo0, srcB), b2 = __shfl((int)hi0, srcB);
  int a3 = __shfl((int)lo1, srcB), b3 = __shfl((int)hi1, srcB);
  union { uint32_t u[4]; s16x8 v; } r;
  r.u[0] = hisel ? (uint32_t)b0 : (uint32_t)a0;
  r.u[1] = hisel ? (uint32_t)b1 : (uint32_t)a1;
  r.u[2] = hisel ? (uint32_t)b2 : (uint32_t)a2;
  r.u[3] = hisel ? (uint32_t)b3 : (uint32_t)a3;
  return r.v;
}

// ---------------- kernel 1: weights f32 -> bf16 ----------------
__global__ void convert_w(const float* __restrict__ wqkv,
                          const float* __restrict__ wout,
                          unsigned short* __restrict__ o) {
  int i = blockIdx.x * 256 + threadIdx.x;           // 262144 total
  if (i < 768 * 256) o[i] = f32_bf16(wqkv[i]);
  else               o[i] = f32_bf16(wout[i - 768 * 256]);
}

// -------- kernel 2: QKV GEMM, x staged ONCE per 128-token block ---------
// 512 threads (8 waves, 2 tok-halves x 4 wcol-quarters). x tile [128][256]
// bf16 in 64KB LDS; 3 passes (q,k,v) x 8 K-steps; weight b128 fragments
// straight from global (L2-resident, 393KB total); no barriers in loop.
// Swapped-operand MFMA -> C[wcol][tok]; q,k to d_out regions, v to ws.
__global__ __launch_bounds__(512) void qkv_gemm(
    const float* __restrict__ x,           // [131072][256] f32
    const unsigned short* __restrict__ wq, // [768][256] bf16
    unsigned short* qk_out,                // d_out: per group 64KB {q|k}
    unsigned short* v_out) {               // ws: per group 32KB v[t64][256]
  __shared__ unsigned short xs[128 * 256];  // 64 KB
  const int bm = blockIdx.x;
  const int tid = threadIdx.x;
  const int w = tid >> 6, lane = tid & 63;
  const int l15 = lane & 15, l4 = lane >> 4;
  const int wr = w >> 2, wc = w & 3;

  // ---- stage x: one full row (1KB) per wave-instruction, fully coalesced
  {
    const float* srcw = x + (size_t)(bm * 128 + w * 16) * 256 + lane * 4;
#pragma unroll
    for (int j = 0; j < 16; ++j) {
      int row = w * 16 + j;
      float4 f = *(const float4*)(srcw + j * 256);
      uint32_t byte = ((uint32_t)(row * 512 + lane * 8)) ^ ((uint32_t)(row & 7) << 4);
      *(uint2*)((char*)xs + byte) = make_uint2(pack_bf16(f.x, f.y), pack_bf16(f.z, f.w));
    }
  }
  __syncthreads();

  const int g = bm * 2 + wr;   // group this wave's tokens belong to

#pragma unroll 1
  for (int p = 0; p < 3; ++p) {   // 0=q, 1=k, 2=v
    const unsigned short* wbase = wq + (size_t)(p * 256 + wc * 64 + l15) * 256 + l4 * 8;
    f32x4 acc[4][4];
#pragma unroll
    for (int mi = 0; mi < 4; ++mi)
#pragma unroll
      for (int ni = 0; ni < 4; ++ni) acc[mi][ni] = (f32x4){0.f, 0.f, 0.f, 0.f};

#pragma unroll
    for (int kk = 0; kk < 8; ++kk) {
      s16x8 af[4], bf[4];
#pragma unroll
      for (int mi = 0; mi < 4; ++mi)
        af[mi] = *(const s16x8*)(wbase + (size_t)(16 * mi) * 256 + kk * 32);
#pragma unroll
      for (int ni = 0; ni < 4; ++ni) {
        int row = wr * 64 + 16 * ni + l15;
        uint32_t byte = (uint32_t)(row * 512 + kk * 64 + l4 * 16) ^ ((uint32_t)(row & 7) << 4);
        bf[ni] = *(const s16x8*)((const char*)xs + byte);
      }
#pragma unroll
      for (int mi = 0; mi < 4; ++mi)
#pragma unroll
        for (int ni = 0; ni < 4; ++ni)
          acc[mi][ni] = __builtin_amdgcn_mfma_f32_16x16x32_bf16(af[mi], bf[ni], acc[mi][ni], 0, 0, 0);
    }

    // store C[wcol][tok]: wcol = wc*64 + 16mi + 4*l4 + r, tok = 16ni + l15
    char* base = (p == 0) ? ((char*)qk_out + ((size_t)g << 16))
               : (p == 1) ? ((char*)qk_out + ((size_t)g << 16) + 32768)
                          : ((char*)v_out + ((size_t)g << 15));
    const int colb = wc * 64 + 4 * l4;
#pragma unroll
    for (int mi = 0; mi < 4; ++mi)
#pragma unroll
      for (int ni = 0; ni < 4; ++ni) {
        uint2 st = make_uint2(pack_bf16(acc[mi][ni][0], acc[mi][ni][1]),
                              pack_bf16(acc[mi][ni][2], acc[mi][ni][3]));
        *(uint2*)(base + (16 * ni + l15) * 512 + (colb + 16 * mi) * 2) = st;
      }
  }
}

// -------- kernel 3: attention + out-projection, block per group ---------
// (verbatim from R7 — it ran at ~84% of its own HBM roofline)
__global__ __launch_bounds__(512) void attn_proj(
    const unsigned short* qk,              // d_out scratch (aliases out!)
    const unsigned short* __restrict__ v_buf,
    const unsigned short* __restrict__ wo, // [256][256] bf16
    const float* __restrict__ bias,
    float* out) {
  __shared__ unsigned short ot[64 * 256];  // 32 KB attn-out tile, swz rows

  const int g    = blockIdx.x;
  const int tid  = threadIdx.x;
  const int h    = tid >> 6;
  const int lane = tid & 63;
  const int l15  = lane & 15;
  const int l4   = lane >> 4;
  const int      srcA  = l15 + ((lane & 16) << 1);
  const int      srcB  = srcA + 16;
  const uint32_t hisel = (uint32_t)(lane & 32);

  const char* qbase = (const char*)qk + ((size_t)g << 16);
  const int hcolb = (h * 32 + l4 * 8) * 2;

  // ---- load q,k fragments (b128 global) ----
  s16x8 kA[4], qB[4];
#pragma unroll
  for (int mb = 0; mb < 4; ++mb)
    kA[mb] = *(const s16x8*)(qbase + 32768 + (16 * mb + l15) * 512 + hcolb);
#pragma unroll
  for (int nb = 0; nb < 4; ++nb)
    qB[nb] = *(const s16x8*)(qbase + (16 * nb + l15) * 512 + hcolb);

  // ---- load v fragments (scalar u16, B-frag: lane=d col, k=ktok) ----
  s16x8 vB[2][2];
  const char* vb0 = (const char*)v_buf + ((size_t)g << 15);
#pragma unroll
  for (int kk2 = 0; kk2 < 2; ++kk2)
#pragma unroll
    for (int t = 0; t < 2; ++t) {
      union { unsigned short u[8]; s16x8 v; } uv;
      const char* vp = vb0 + (kk2 * 32 + 8 * l4) * 512 + (h * 32 + 16 * t + l15) * 2;
#pragma unroll
      for (int j = 0; j < 8; ++j)
        uv.u[j] = *(const unsigned short*)(vp + j * 512);
      vB[kk2][t] = uv.v;
    }

  // ---- per q-block: energy^T -> softmax -> PV -> LDS store ----
#pragma unroll
  for (int nb = 0; nb < 4; ++nb) {
    f32x4 en[4];
#pragma unroll
    for (int mb = 0; mb < 4; ++mb) {
      en[mb] = (f32x4){0.f, 0.f, 0.f, 0.f};
      en[mb] = __builtin_amdgcn_mfma_f32_16x16x32_bf16(kA[mb], qB[nb], en[mb], 0, 0, 0);
    }
    float mx = en[0][0];
#pragma unroll
    for (int mb = 0; mb < 4; ++mb)
#pragma unroll
      for (int r = 0; r < 4; ++r) mx = fmaxf(mx, en[mb][r]);
    mx = fmaxf(mx, __shfl_xor(mx, 16));
    mx = fmaxf(mx, __shfl_xor(mx, 32));
    float p[4][4];
    float sum = 0.f;
#pragma unroll
    for (int mb = 0; mb < 4; ++mb)
#pragma unroll
      for (int r = 0; r < 4; ++r) {
        float t = __expf((en[mb][r] - mx) * 0.0625f);  // scale 1/sqrt(256)
        p[mb][r] = t;
        sum += t;
      }
    sum += __shfl_xor(sum, 16);
    sum += __shfl_xor(sum, 32);
    float rs = 1.0f / sum;
    uint32_t pk[4][2];
#pragma unroll
    for (int mb = 0; mb < 4; ++mb) {
      pk[mb][0] = pack_bf16(p[mb][0] * rs, p[mb][1] * rs);
      pk[mb][1] = pack_bf16(p[mb][2] * rs, p[mb][3] * rs);
    }
    f32x4 o0 = (f32x4){0.f, 0.f, 0.f, 0.f};
    f32x4 o1 = (f32x4){0.f, 0.f, 0.f, 0.f};
#pragma unroll
    for (int kk2 = 0; kk2 < 2; ++kk2) {
      s16x8 pA = xchg(pk[2 * kk2][0], pk[2 * kk2][1],
                      pk[2 * kk2 + 1][0], pk[2 * kk2 + 1][1], srcA, srcB, hisel);
      o0 = __builtin_amdgcn_mfma_f32_16x16x32_bf16(pA, vB[kk2][0], o0, 0, 0, 0);
      o1 = __builtin_amdgcn_mfma_f32_16x16x32_bf16(pA, vB[kk2][1], o1, 0, 0, 0);
    }
#pragma unroll
    for (int r = 0; r < 4; ++r) {
      int row = 16 * nb + 4 * l4 + r;
      uint32_t rsw = (uint32_t)(row & 7) << 4;
      uint32_t c0 = ((uint32_t)(row * 512 + (h * 32 + l15) * 2)) ^ rsw;
      uint32_t c1 = ((uint32_t)(row * 512 + (h * 32 + 16 + l15) * 2)) ^ rsw;
      *(unsigned short*)((char*)ot + c0) = f32_bf16(o0[r]);
      *(unsigned short*)((char*)ot + c1) = f32_bf16(o1[r]);
    }
  }
  __syncthreads();

  // ---- projection: wave h -> out cols [h*32, h*32+32), swapped C ----
  f32x4 acc2[2][4];
#pragma unroll
  for (int mi = 0; mi < 2; ++mi)
#pragma unroll
    for (int ni = 0; ni < 4; ++ni) acc2[mi][ni] = (f32x4){0.f, 0.f, 0.f, 0.f};

#pragma unroll
  for (int kk = 0; kk < 8; ++kk) {
    s16x8 af[2], bfrag[4];
#pragma unroll
    for (int mi = 0; mi < 2; ++mi)
      af[mi] = *(const s16x8*)(wo + (size_t)(h * 32 + 16 * mi + l15) * 256 + kk * 32 + l4 * 8);
#pragma unroll
    for (int ni = 0; ni < 4; ++ni) {
      uint32_t byte = ((uint32_t)((16 * ni + l15) * 512 + (kk * 32 + l4 * 8) * 2)) ^ ((uint32_t)(l15 & 7) << 4);
      bfrag[ni] = *(const s16x8*)((const char*)ot + byte);
    }
#pragma unroll
    for (int mi = 0; mi < 2; ++mi)
#pragma unroll
      for (int ni = 0; ni < 4; ++ni)
        acc2[mi][ni] = __builtin_amdgcn_mfma_f32_16x16x32_bf16(af[mi], bfrag[ni], acc2[mi][ni], 0, 0, 0);
  }

#pragma unroll
  for (int mi = 0; mi < 2; ++mi) {
    const int oc = h * 32 + 16 * mi + 4 * l4;
    float4 bb = *(const float4*)(bias + oc);
#pragma unroll
    for (int ni = 0; ni < 4; ++ni) {
      float4 st;
      st.x = acc2[mi][ni][0] + bb.x;
      st.y = acc2[mi][ni][1] + bb.y;
      st.z = acc2[mi][ni][2] + bb.z;
      st.w = acc2[mi][ni][3] + bb.w;
      *(float4*)(out + (size_t)(g * 64 + 16 * ni + l15) * 256 + oc) = st;
    }
  }
}

extern "C" void kernel_launch(void* const* d_in, const int* in_sizes, int n_in,
                              void* d_out, int out_size, void* d_ws, size_t ws_size,
                              hipStream_t stream) {
  const float* x    = (const float*)d_in[0];
  const float* wqkv = (const float*)d_in[1];
  const float* wout = (const float*)d_in[2];
  const float* bout = (const float*)d_in[3];
  float* out = (float*)d_out;

  unsigned short* wq_bf = (unsigned short*)d_ws;          // 768*256 bf16
  unsigned short* wo_bf = wq_bf + 768 * 256;              // 256*256 bf16
  unsigned short* v_buf = wo_bf + 256 * 256;              // 2048 groups * 32KB

  convert_w<<<1024, 256, 0, stream>>>(wqkv, wout, wq_bf);
  qkv_gemm<<<1024, 512, 0, stream>>>(x, wq_bf, (unsigned short*)d_out, v_buf);
  attn_proj<<<2048, 512, 0, stream>>>((const unsigned short*)d_out, v_buf, wo_bf, bout, out);
}